// Round 3
// baseline (341.950 us; speedup 1.0000x reference)
//
#include <hip/hip_runtime.h>
#include <hip/hip_bf16.h>

#define K_DIM 4096

typedef float f32x4 __attribute__((ext_vector_type(4)));

// One wave (64 lanes) computes one output row: two dot-products of length 4096.
// Lanes stride over K with float4 loads (16 B/lane -> 1 KiB/instruction, fully
// coalesced). A is read exactly once -> NONTEMPORAL loads (nt flag) so the
// 1 GB stream doesn't thrash L2; W (32 KB, read by every block) keeps normal
// loads and stays L2-resident. W staged per-block into LDS, column-split so
// LDS reads are contiguous b128 (conflict-free). Grid-stride over rows.
//
// NO __launch_bounds__: R2 showed capping VGPR at 128 causes a 1.66x
// regression (spill / serialized load stream). Compiler needs VGPR freedom
// to keep the 16-deep unrolled load stream in flight.
__global__ void moe_rowdot_kernel(
    const float* __restrict__ A,   // [BATCH][K_DIM]
    const float* __restrict__ W,   // [K_DIM][2]
    float* __restrict__ out,       // [BATCH][2]
    int batch) {

    __shared__ float w0[K_DIM];
    __shared__ float w1[K_DIM];

    // Stage W into LDS (column-split). Normal (cached) loads: L2-resident.
    for (int i = threadIdx.x; i < K_DIM; i += blockDim.x) {
        float2 wv = reinterpret_cast<const float2*>(W)[i];
        w0[i] = wv.x;
        w1[i] = wv.y;
    }
    __syncthreads();

    const int lane          = threadIdx.x & 63;
    const int waveInBlock   = threadIdx.x >> 6;
    const int wavesPerBlock = blockDim.x >> 6;
    const int globalWave    = blockIdx.x * wavesPerBlock + waveInBlock;
    const int numWaves      = gridDim.x * wavesPerBlock;

    const f32x4* w0v = reinterpret_cast<const f32x4*>(w0);
    const f32x4* w1v = reinterpret_cast<const f32x4*>(w1);

    for (int row = globalWave; row < batch; row += numWaves) {
        const f32x4* arow =
            reinterpret_cast<const f32x4*>(A + (size_t)row * K_DIM);
        float acc0 = 0.f, acc1 = 0.f;
        // K_DIM / (64 lanes * 4 floats) = 16 iterations
        #pragma unroll
        for (int it = 0; it < K_DIM / 256; ++it) {
            const int idx = it * 64 + lane;      // float4 index
            f32x4 a  = __builtin_nontemporal_load(&arow[idx]);  // stream, don't cache
            f32x4 b0 = w0v[idx];
            f32x4 b1 = w1v[idx];
            acc0 += a.x * b0.x + a.y * b0.y + a.z * b0.z + a.w * b0.w;
            acc1 += a.x * b1.x + a.y * b1.y + a.z * b1.z + a.w * b1.w;
        }
        // Wave-wide reduction (64 lanes).
        #pragma unroll
        for (int off = 32; off > 0; off >>= 1) {
            acc0 += __shfl_xor(acc0, off);
            acc1 += __shfl_xor(acc1, off);
        }
        if (lane == 0) {
            reinterpret_cast<float2*>(out)[row] = make_float2(acc0, acc1);
        }
    }
}

extern "C" void kernel_launch(void* const* d_in, const int* in_sizes, int n_in,
                              void* d_out, int out_size, void* d_ws, size_t ws_size,
                              hipStream_t stream) {
    const float* A = (const float*)d_in[0];   // router_weights [65536][4096]
    const float* W = (const float*)d_in[1];   // W_values [4096][2]
    float* out = (float*)d_out;               // [65536][2]

    const int batch = in_sizes[0] / K_DIM;    // 65536

    // 2048 blocks x 256 threads = 8192 waves; exactly 8 rows per wave,
    // perfectly balanced. (R1 config — known good at 201.7 us.)
    const int blocks = 2048;
    moe_rowdot_kernel<<<blocks, 256, 0, stream>>>(A, W, out, batch);
}